// Round 11
// baseline (151.933 us; speedup 1.0000x reference)
//
#include <hip/hip_runtime.h>
#include <math.h>

#define NTOT 8704
#define BANKN 8192
#define NB 512
#define DIM 128
#define INVT (1.0f / 0.07f)
#define C2L 20.6099131801f  // (1/0.07) * log2(e)
#define NCHUNK 17
#define TPC 8               // col tiles per chunk (17*8*64 = 8704)
#define BN 64               // cols per tile

using short8 = __attribute__((ext_vector_type(8))) short;
using ushort8 = __attribute__((ext_vector_type(8))) unsigned short;
using f32x4 = __attribute__((ext_vector_type(4))) float;

static __device__ __forceinline__ ushort f2bf(float f) {
  union { float f; unsigned u; } v;
  v.f = f;
  unsigned r = v.u + 0x7fffu + ((v.u >> 16) & 1u);  // RNE
  return (ushort)(r >> 16);
}

static __device__ __forceinline__ float fast_exp2(float x) {
#if __has_builtin(__builtin_amdgcn_exp2f)
  return __builtin_amdgcn_exp2f(x);
#else
  return exp2f(x);
#endif
}

// ---------------- prep: counting sort via 16 per-wave sub-histograms --------
__global__ __launch_bounds__(1024) void prep_kernel(
    const int* __restrict__ bank_labels, const int* __restrict__ label,
    int* __restrict__ inv, int* __restrict__ lo, int* __restrict__ hi) {
  __shared__ int h[16][100];
  __shared__ int st[101];
  __shared__ int sc[128];
  const int tid = threadIdx.x;
  const int w = tid >> 6;
  for (int i = tid; i < 1600; i += 1024) (&h[0][0])[i] = 0;
  __syncthreads();
  for (int i = tid; i < NTOT; i += 1024) {
    const int v = (i < BANKN) ? bank_labels[i] : label[i - BANKN];
    atomicAdd(&h[w][v], 1);
  }
  __syncthreads();
  int tot = 0;
  if (tid < 128) {
    if (tid < 100) {
#pragma unroll
      for (int w2 = 0; w2 < 16; ++w2) tot += h[w2][tid];
    }
    sc[tid] = tot;
  }
  __syncthreads();
#pragma unroll
  for (int off = 1; off < 128; off <<= 1) {
    int add = 0;
    if (tid < 128 && tid >= off) add = sc[tid - off];
    __syncthreads();
    if (tid < 128) sc[tid] += add;
    __syncthreads();
  }
  if (tid < 100) {
    st[tid] = sc[tid] - tot;  // exclusive
    if (tid == 99) st[100] = sc[99];
  }
  __syncthreads();
  if (tid < 100) {
    int base = st[tid];
#pragma unroll
    for (int w2 = 0; w2 < 16; ++w2) {
      const int t = h[w2][tid];
      h[w2][tid] = base;
      base += t;
    }
  }
  __syncthreads();
  for (int i = tid; i < NTOT; i += 1024) {
    const int v = (i < BANKN) ? bank_labels[i] : label[i - BANKN];
    const int p = atomicAdd(&h[w][v], 1);
    inv[i] = p;
    lo[p] = st[v];
    hi[p] = st[v + 1];
  }
}

// ---------------- pack: coalesced transpose + sorted row scatter; zero zp ---
__global__ void pack_kernel(const float* __restrict__ features,
                            const float* __restrict__ bank1,
                            const float* __restrict__ bank2,
                            const int* __restrict__ inv,
                            ushort* __restrict__ cf1b,
                            ushort* __restrict__ cf2b,
                            float* __restrict__ zp) {
  const int branch = blockIdx.z;
  ushort* __restrict__ dst = branch ? cf2b : cf1b;
  const int tx = threadIdx.x, ty = threadIdx.y;
  const int bx = blockIdx.x, by = blockIdx.y;
  const int tid = ty * 32 + tx;
  if (branch == 0 && by == 0 && bx < 34) {
    const int i = bx * 256 + tid;  // 34*256 == NTOT
    reinterpret_cast<float4*>(zp)[i] = make_float4(0.f, 0.f, 0.f, 0.f);
  }
  if (bx < 256) {
    const float* __restrict__ src = branch ? bank1 : bank2;
    __shared__ float tile[32][33];
    const int col = bx * 32 + tx;
#pragma unroll
    for (int s = 0; s < 32; s += 8)
      tile[ty + s][tx] = src[(size_t)(by * 32 + ty + s) * BANKN + col];
    __syncthreads();
    const int k = by * 32 + tx;
#pragma unroll
    for (int s = 0; s < 32; s += 8) {
      const int p = inv[bx * 32 + ty + s];
      dst[(size_t)p * DIM + k] = f2bf(tile[tx][ty + s]);
    }
  } else {
#pragma unroll
    for (int s = 0; s < 32; s += 8) {
      const int jr = (bx - 256) * 32 + ty + s;
      const int k = by * 32 + tx;
      const float v = features[(size_t)(branch * NB + jr) * DIM + k];
      const int p = inv[BANKN + jr];
      dst[(size_t)p * DIM + k] = f2bf(v);
    }
  }
}

// ---------------- main: MFMA with 2-acc tile pipeline -----------------------
// 2 LDS buffers; per tile-pair: {bar; STAGE; MFMA(t+1)->accB; EPI(t)<-accA}
// so epilogue VALU/trans overlaps the next tile's MFMA (separate pipes).
__global__ __launch_bounds__(256) void supcon_mfma_kernel(
    const ushort* __restrict__ cf1b, const ushort* __restrict__ cf2b,
    const int* __restrict__ lo, const int* __restrict__ hi,
    float* __restrict__ zp) {
  const int rb = blockIdx.x;      // 0..67 row block (128 rows)
  const int chunk = blockIdx.y;   // 0..16
  const int branch = blockIdx.z;  // 0..1
  const ushort* __restrict__ cf = branch ? cf2b : cf1b;

  const int tid = threadIdx.x;
  const int wid = tid >> 6, lane = tid & 63;
  const int l15 = lane & 15, l4 = lane >> 4;
  const int rowW = rb * 128 + wid * 32;  // wave owns rows [rowW, rowW+32)

  __shared__ ushort Bt[2][BN * DIM];  // 2 x 16KB

  // ---- A fragments: 32 rows x K=128 per wave ----
  short8 a[2][4];
#pragma unroll
  for (int rt = 0; rt < 2; ++rt) {
    const int r = rowW + rt * 16 + l15;
#pragma unroll
    for (int ks = 0; ks < 4; ++ks)
      a[rt][ks] = *reinterpret_cast<const short8*>(cf + (size_t)r * DIM + ks * 32 + l4 * 8);
  }
  int rlo[2][4], rhi[2][4];
#pragma unroll
  for (int rt = 0; rt < 2; ++rt)
#pragma unroll
    for (int rg = 0; rg < 4; ++rg) {
      const int rr = rowW + rt * 16 + l4 * 4 + rg;
      rlo[rt][rg] = lo[rr];
      rhi[rt][rg] = hi[rr];
    }
  const int u_lo = lo[rowW];
  const int u_hi = hi[rowW + 31];
  const int lo_last = lo[rowW + 31];
  const int hi_first = hi[rowW];

  float Zr[2][4] = {};
  float Pr[2][4] = {};

  auto STAGE = [&](int t) {
    const int col0 = (chunk * TPC + t) * BN;
    const int buf = t & 1;
#pragma unroll
    for (int it = 0; it < 4; ++it) {
      const int o = it * 256 + tid;  // 16B-chunk index 0..1023
      const int row = o >> 4, cc = o & 15;
      const ushort* src =
          cf + (size_t)(col0 + row) * DIM + ((cc ^ (row & 15)) * 8);
      ushort* dst = &Bt[buf][(it * 256 + wid * 64) * 8];
      __builtin_amdgcn_global_load_lds(
          (const __attribute__((address_space(1))) void*)src,
          (__attribute__((address_space(3))) void*)dst, 16, 0, 0);
    }
  };

  // MFMA for one tile into the given acc (reads Bt[t&1])
  auto MFMA_TILE = [&](int t, f32x4 (&acc)[2][4]) {
    const ushort* __restrict__ B = &Bt[t & 1][0];
#pragma unroll
    for (int rt = 0; rt < 2; ++rt)
#pragma unroll
      for (int ct = 0; ct < 4; ++ct) acc[rt][ct] = (f32x4){0.f, 0.f, 0.f, 0.f};
#pragma unroll
    for (int ks = 0; ks < 4; ++ks) {
      short8 b[4];
#pragma unroll
      for (int ct = 0; ct < 4; ++ct) {
        const int r = ct * 16 + l15;
        const int swz = (ks * 4 + l4) ^ l15;  // (r&15)==l15
        b[ct] = *reinterpret_cast<const short8*>(&B[r * DIM + swz * 8]);
      }
#pragma unroll
      for (int rt = 0; rt < 2; ++rt)
#pragma unroll
        for (int ct = 0; ct < 4; ++ct)
          acc[rt][ct] = __builtin_amdgcn_mfma_f32_16x16x32_bf16(
              a[rt][ks], b[ct], acc[rt][ct], 0, 0, 0);
    }
  };

  // epilogue for one tile from the given acc
  auto EPI = [&](int t, f32x4 (&acc)[2][4]) {
    const int col0 = (chunk * TPC + t) * BN;
    if (col0 + BN <= u_lo || col0 >= u_hi) {
#pragma unroll
      for (int ct = 0; ct < 4; ++ct)
#pragma unroll
        for (int rt = 0; rt < 2; ++rt)
#pragma unroll
          for (int rg = 0; rg < 4; ++rg)
            Zr[rt][rg] += fast_exp2(fmaf(acc[rt][ct][rg], C2L, -C2L));
    } else if (col0 >= lo_last && col0 + BN <= hi_first) {
#pragma unroll
      for (int ct = 0; ct < 4; ++ct)
#pragma unroll
        for (int rt = 0; rt < 2; ++rt)
#pragma unroll
          for (int rg = 0; rg < 4; ++rg) Pr[rt][rg] += acc[rt][ct][rg];
    } else {
#pragma unroll
      for (int ct = 0; ct < 4; ++ct) {
        const int c = col0 + ct * 16 + l15;
#pragma unroll
        for (int rt = 0; rt < 2; ++rt)
#pragma unroll
          for (int rg = 0; rg < 4; ++rg) {
            const float v = acc[rt][ct][rg];
            const float e = fast_exp2(fmaf(v, C2L, -C2L));
            const bool s = (c >= rlo[rt][rg]) && (c < rhi[rt][rg]);
            Zr[rt][rg] += s ? 0.0f : e;
            Pr[rt][rg] += s ? v : 0.0f;
          }
      }
    }
  };

  f32x4 accA[2][4], accB[2][4];

  STAGE(0);
  asm volatile("s_waitcnt vmcnt(0)" ::: "memory");
  __builtin_amdgcn_s_barrier();
  STAGE(1);
  MFMA_TILE(0, accA);  // ds_reads of buf0 + mfma into accA (in flight)

  for (int tp = 0; tp < TPC; tp += 2) {
    // phase 1: tile tp+1 data ready; my buf0 ds_reads drained
    asm volatile("s_waitcnt vmcnt(0) lgkmcnt(0)" ::: "memory");
    __builtin_amdgcn_s_barrier();
    if (tp + 2 < TPC) STAGE(tp + 2);       // overwrites buf0
    MFMA_TILE(tp + 1, accB);               // reads buf1
    EPI(tp, accA);                         // VALU/trans overlaps accB MFMAs

    // phase 2: tile tp+2 data ready; my buf1 ds_reads drained
    asm volatile("s_waitcnt vmcnt(0) lgkmcnt(0)" ::: "memory");
    __builtin_amdgcn_s_barrier();
    if (tp + 3 < TPC) STAGE(tp + 3);       // overwrites buf1
    if (tp + 2 < TPC) MFMA_TILE(tp + 2, accA);  // reads buf0
    EPI(tp + 1, accB);
  }

  // ---- cross-lane reduce over l15 group, then atomic accumulate ----
  float* Zrow = zp;             // [2][NTOT]
  float* Prow = zp + 2 * NTOT;  // [2][NTOT]
#pragma unroll
  for (int rt = 0; rt < 2; ++rt)
#pragma unroll
    for (int rg = 0; rg < 4; ++rg) {
      float z = Zr[rt][rg], p = Pr[rt][rg];
#pragma unroll
      for (int off = 1; off < 16; off <<= 1) {
        z += __shfl_xor(z, off);
        p += __shfl_xor(p, off);
      }
      if (l15 == 0) {
        const int row = rowW + rt * 16 + l4 * 4 + rg;
        atomicAdd(&Zrow[branch * NTOT + row], z);
        atomicAdd(&Prow[branch * NTOT + row], p);
      }
    }
}

// ---------------- loss: per-row loss -> scalar (single block) ---------------
__global__ __launch_bounds__(1024) void loss_kernel(const float* __restrict__ zp,
                                                    const int* __restrict__ lo,
                                                    const int* __restrict__ hi,
                                                    float* __restrict__ out) {
  const int tid = threadIdx.x;
  const float* Zrow = zp;
  const float* Prow = zp + 2 * NTOT;
  float local = 0.f;
  for (int idx = tid; idx < 2 * NTOT; idx += 1024) {
    const int row = (idx >= NTOT) ? idx - NTOT : idx;
    const float z = Zrow[idx];
    const float p = Prow[idx];
    const float C = (float)(hi[row] - lo[row] - 1);
    const float denom = INVT + logf(z);
    local += -((INVT * (p - 1.0f)) / C - denom);
  }
  __shared__ float s[1024];
  s[tid] = local;
  __syncthreads();
  for (int st = 512; st > 0; st >>= 1) {
    if (tid < st) s[tid] += s[tid + st];
    __syncthreads();
  }
  if (tid == 0) {
    const float v = s[0] / (2.0f * NTOT);
    out[0] = v; out[1] = v; out[2] = v;
  }
}

// ---------------------------------------------------------------------------
extern "C" void kernel_launch(void* const* d_in, const int* in_sizes, int n_in,
                              void* d_out, int out_size, void* d_ws,
                              size_t ws_size, hipStream_t stream) {
  const float* features = (const float*)d_in[0];  // (1024,1,128) f32
  const int* label = (const int*)d_in[1];         // (512,) i32
  const float* bank1 = (const float*)d_in[2];     // (128,8192) f32
  const float* bank2 = (const float*)d_in[3];     // (128,8192) f32
  const int* bank_labels = (const int*)d_in[4];   // (8192,) i32
  float* out = (float*)d_out;

  char* ws = (char*)d_ws;
  ushort* cf1b = (ushort*)(ws);            // 2,228,224 B
  ushort* cf2b = (ushort*)(ws + 2228224);  // 2,228,224 B
  int* inv = (int*)(ws + 4456448);         // 34,816 B
  int* lo = (int*)(ws + 4491264);          // 34,816 B
  int* hi = (int*)(ws + 4526080);          // 34,816 B
  float* zp = (float*)(ws + 4560896);      // 139,264 B (Z[2][N], P[2][N])

  prep_kernel<<<dim3(1), dim3(1024), 0, stream>>>(bank_labels, label, inv, lo,
                                                  hi);
  pack_kernel<<<dim3(272, DIM / 32, 2), dim3(32, 8), 0, stream>>>(
      features, bank1, bank2, inv, cf1b, cf2b, zp);
  supcon_mfma_kernel<<<dim3(NTOT / 128, NCHUNK, 2), dim3(256), 0, stream>>>(
      cf1b, cf2b, lo, hi, zp);
  loss_kernel<<<dim3(1), dim3(1024), 0, stream>>>(zp, lo, hi, out);
}

// Round 13
// 141.571 us; speedup vs baseline: 1.0732x; 1.0732x over previous
//
#include <hip/hip_runtime.h>
#include <math.h>

#define NTOT 8704
#define BANKN 8192
#define NB 512
#define DIM 128
#define INVT (1.0f / 0.07f)
#define C2L 20.6099131801f  // (1/0.07) * log2(e)
#define NCHUNK 17
#define TPC 8               // col tiles per chunk (17*8*64 = 8704)
#define BN 64               // cols per tile

using short8 = __attribute__((ext_vector_type(8))) short;
using ushort8 = __attribute__((ext_vector_type(8))) unsigned short;
using f32x4 = __attribute__((ext_vector_type(4))) float;
using f32x2 = __attribute__((ext_vector_type(2))) float;

static __device__ __forceinline__ ushort f2bf(float f) {
  union { float f; unsigned u; } v;
  v.f = f;
  unsigned r = v.u + 0x7fffu + ((v.u >> 16) & 1u);  // RNE
  return (ushort)(r >> 16);
}

static __device__ __forceinline__ float fast_exp2(float x) {
#if __has_builtin(__builtin_amdgcn_exp2f)
  return __builtin_amdgcn_exp2f(x);
#else
  return exp2f(x);
#endif
}

// ---------------- prep: counting sort via 16 per-wave sub-histograms --------
__global__ __launch_bounds__(1024) void prep_kernel(
    const int* __restrict__ bank_labels, const int* __restrict__ label,
    int* __restrict__ inv, int* __restrict__ lo, int* __restrict__ hi) {
  __shared__ int h[16][100];
  __shared__ int st[101];
  __shared__ int sc[128];
  const int tid = threadIdx.x;
  const int w = tid >> 6;
  for (int i = tid; i < 1600; i += 1024) (&h[0][0])[i] = 0;
  __syncthreads();
  for (int i = tid; i < NTOT; i += 1024) {
    const int v = (i < BANKN) ? bank_labels[i] : label[i - BANKN];
    atomicAdd(&h[w][v], 1);
  }
  __syncthreads();
  int tot = 0;
  if (tid < 128) {
    if (tid < 100) {
#pragma unroll
      for (int w2 = 0; w2 < 16; ++w2) tot += h[w2][tid];
    }
    sc[tid] = tot;
  }
  __syncthreads();
#pragma unroll
  for (int off = 1; off < 128; off <<= 1) {
    int add = 0;
    if (tid < 128 && tid >= off) add = sc[tid - off];
    __syncthreads();
    if (tid < 128) sc[tid] += add;
    __syncthreads();
  }
  if (tid < 100) {
    st[tid] = sc[tid] - tot;  // exclusive
    if (tid == 99) st[100] = sc[99];
  }
  __syncthreads();
  if (tid < 100) {
    int base = st[tid];
#pragma unroll
    for (int w2 = 0; w2 < 16; ++w2) {
      const int t = h[w2][tid];
      h[w2][tid] = base;
      base += t;
    }
  }
  __syncthreads();
  for (int i = tid; i < NTOT; i += 1024) {
    const int v = (i < BANKN) ? bank_labels[i] : label[i - BANKN];
    const int p = atomicAdd(&h[w][v], 1);
    inv[i] = p;
    lo[p] = st[v];
    hi[p] = st[v + 1];
  }
}

// ---------------- pack: coalesced transpose + sorted row scatter; zero zp ---
__global__ void pack_kernel(const float* __restrict__ features,
                            const float* __restrict__ bank1,
                            const float* __restrict__ bank2,
                            const int* __restrict__ inv,
                            ushort* __restrict__ cf1b,
                            ushort* __restrict__ cf2b,
                            float* __restrict__ zp) {
  const int branch = blockIdx.z;
  ushort* __restrict__ dst = branch ? cf2b : cf1b;
  const int tx = threadIdx.x, ty = threadIdx.y;
  const int bx = blockIdx.x, by = blockIdx.y;
  const int tid = ty * 32 + tx;
  if (branch == 0 && by == 0 && bx < 34) {
    const int i = bx * 256 + tid;  // 34*256 == NTOT
    reinterpret_cast<float4*>(zp)[i] = make_float4(0.f, 0.f, 0.f, 0.f);
  }
  if (bx < 256) {
    const float* __restrict__ src = branch ? bank1 : bank2;
    __shared__ float tile[32][33];
    const int col = bx * 32 + tx;
#pragma unroll
    for (int s = 0; s < 32; s += 8)
      tile[ty + s][tx] = src[(size_t)(by * 32 + ty + s) * BANKN + col];
    __syncthreads();
    const int k = by * 32 + tx;
#pragma unroll
    for (int s = 0; s < 32; s += 8) {
      const int p = inv[bx * 32 + ty + s];
      dst[(size_t)p * DIM + k] = f2bf(tile[tx][ty + s]);
    }
  } else {
#pragma unroll
    for (int s = 0; s < 32; s += 8) {
      const int jr = (bx - 256) * 32 + ty + s;
      const int k = by * 32 + tx;
      const float v = features[(size_t)(branch * NB + jr) * DIM + k];
      const int p = inv[BANKN + jr];
      dst[(size_t)p * DIM + k] = f2bf(v);
    }
  }
}

// ---------------- main: MFMA + interval-sorted masked reductions ------------
// r10 schedule (2-buffer, vmcnt(0)+raw barrier, stage-after-barrier) with the
// per-tile address arithmetic hoisted: ds_reads = 4 base regs + immediates,
// STAGE = 4 persistent pointers (+16KB/tile), tile loop unrolled x2.
__global__ __launch_bounds__(256) void supcon_mfma_kernel(
    const ushort* __restrict__ cf1b, const ushort* __restrict__ cf2b,
    const int* __restrict__ lo, const int* __restrict__ hi,
    float* __restrict__ zp) {
  const int rb = blockIdx.x;      // 0..67 row block (128 rows)
  const int chunk = blockIdx.y;   // 0..16
  const int branch = blockIdx.z;  // 0..1
  const ushort* __restrict__ cf = branch ? cf2b : cf1b;

  const int tid = threadIdx.x;
  const int wid = tid >> 6, lane = tid & 63;
  const int l15 = lane & 15, l4 = lane >> 4;
  const int rowW = rb * 128 + wid * 32;  // wave owns rows [rowW, rowW+32)

  __shared__ ushort Bt[2][BN * DIM];  // 2 x 16KB

  // ---- A fragments: 32 rows x K=128 per wave ----
  short8 a[2][4];
#pragma unroll
  for (int rt = 0; rt < 2; ++rt) {
    const int r = rowW + rt * 16 + l15;
#pragma unroll
    for (int ks = 0; ks < 4; ++ks)
      a[rt][ks] = *reinterpret_cast<const short8*>(cf + (size_t)r * DIM + ks * 32 + l4 * 8);
  }
  int rlo[2][4], rhi[2][4];
#pragma unroll
  for (int rt = 0; rt < 2; ++rt)
#pragma unroll
    for (int rg = 0; rg < 4; ++rg) {
      const int rr = rowW + rt * 16 + l4 * 4 + rg;
      rlo[rt][rg] = lo[rr];
      rhi[rt][rg] = hi[rr];
    }
  const int u_lo = lo[rowW];
  const int u_hi = hi[rowW + 31];
  const int lo_last = lo[rowW + 31];
  const int hi_first = hi[rowW];

  f32x2 Zr[2][2] = {};  // [rt][rg>>1], component rg&1
  f32x2 Pr[2][2] = {};

  // ---- precomputed ds_read bases: one per ks; ct/buf are immediates ----
  // elem addr = r*DIM + swz*8, r=ct*16+l15, swz=(ks*4|l4)^l15
  //           = l15*DIM + (((ks^(l15>>2))<<2)|(l4^(l15&3)))*8
  //             + ct*16*DIM + buf*BN*DIM
  const ushort* dsbase[4];
#pragma unroll
  for (int ks = 0; ks < 4; ++ks) {
    const int swz = ((ks ^ (l15 >> 2)) << 2) | (l4 ^ (l15 & 3));
    dsbase[ks] = &Bt[0][0] + l15 * DIM + swz * 8;
  }

  // ---- persistent STAGE source pointers (one per 16-row slab) ----
  // row&15 == tid>>4 (lane-constant) -> swz lane-constant
  const int rowL = tid >> 4, ccL = tid & 15;
  const int swzL = ccL ^ rowL;
  const ushort* sp[4];
#pragma unroll
  for (int it = 0; it < 4; ++it)
    sp[it] = cf + (size_t)(chunk * TPC * BN + it * 16 + rowL) * DIM + swzL * 8;

  // stage next pending tile into buf, advance pointers
  auto STAGE = [&](int buf) {
#pragma unroll
    for (int it = 0; it < 4; ++it) {
      ushort* dst = &Bt[buf][(it * 256 + wid * 64) * 8];
      __builtin_amdgcn_global_load_lds(
          (const __attribute__((address_space(1))) void*)sp[it],
          (__attribute__((address_space(3))) void*)dst, 16, 0, 0);
      sp[it] += BN * DIM;  // +8192 elems = +16KB
    }
  };

  STAGE(0);  // tile 0

  int col0 = chunk * TPC * BN;

#define PHASE(TGUARD, BUF)                                                     \
  {                                                                            \
    asm volatile("s_waitcnt vmcnt(0)" ::: "memory");                           \
    __builtin_amdgcn_s_barrier();                                              \
    if (TGUARD) STAGE(BUF ^ 1);                                                \
    f32x4 acc[2][4];                                                           \
    _Pragma("unroll") for (int rt = 0; rt < 2; ++rt)                           \
        _Pragma("unroll") for (int ct = 0; ct < 4; ++ct) acc[rt][ct] =         \
        (f32x4){0.f, 0.f, 0.f, 0.f};                                           \
    _Pragma("unroll") for (int ks = 0; ks < 4; ++ks) {                         \
      short8 b[4];                                                             \
      _Pragma("unroll") for (int ct = 0; ct < 4; ++ct) b[ct] =                 \
          *reinterpret_cast<const short8*>(dsbase[ks] + ct * 16 * DIM +        \
                                           (BUF)*BN * DIM);                    \
      _Pragma("unroll") for (int rt = 0; rt < 2; ++rt)                         \
          _Pragma("unroll") for (int ct = 0; ct < 4; ++ct) acc[rt][ct] =       \
          __builtin_amdgcn_mfma_f32_16x16x32_bf16(a[rt][ks], b[ct],            \
                                                  acc[rt][ct], 0, 0, 0);       \
    }                                                                          \
    if (col0 + BN <= u_lo || col0 >= u_hi) {                                   \
      _Pragma("unroll") for (int ct = 0; ct < 4; ++ct)                         \
          _Pragma("unroll") for (int rt = 0; rt < 2; ++rt)                     \
          _Pragma("unroll") for (int rg = 0; rg < 4; ++rg)                     \
          Zr[rt][rg >> 1][rg & 1] +=                                           \
          fast_exp2(fmaf(acc[rt][ct][rg], C2L, -C2L));                         \
    } else if (col0 >= lo_last && col0 + BN <= hi_first) {                     \
      _Pragma("unroll") for (int ct = 0; ct < 4; ++ct)                         \
          _Pragma("unroll") for (int rt = 0; rt < 2; ++rt)                     \
          _Pragma("unroll") for (int rg = 0; rg < 4; ++rg)                     \
          Pr[rt][rg >> 1][rg & 1] += acc[rt][ct][rg];                          \
    } else {                                                                   \
      _Pragma("unroll") for (int ct = 0; ct < 4; ++ct) {                       \
        const int c = col0 + ct * 16 + l15;                                    \
        _Pragma("unroll") for (int rt = 0; rt < 2; ++rt)                       \
            _Pragma("unroll") for (int rg = 0; rg < 4; ++rg) {                 \
          const float v = acc[rt][ct][rg];                                     \
          const float e = fast_exp2(fmaf(v, C2L, -C2L));                       \
          const bool s = (c >= rlo[rt][rg]) && (c < rhi[rt][rg]);              \
          Zr[rt][rg >> 1][rg & 1] += s ? 0.0f : e;                             \
          Pr[rt][rg >> 1][rg & 1] += s ? v : 0.0f;                             \
        }                                                                      \
      }                                                                        \
    }                                                                          \
    col0 += BN;                                                                \
  }

  for (int tp = 0; tp < TPC; tp += 2) {
    PHASE(tp + 1 < TPC, 0);  // compute even tile from buf0; stage odd -> buf1
    PHASE(tp + 2 < TPC, 1);  // compute odd tile from buf1; stage even -> buf0
  }
#undef PHASE

  // ---- cross-lane reduce over l15 group, then atomic accumulate ----
  float* Zrow = zp;             // [2][NTOT]
  float* Prow = zp + 2 * NTOT;  // [2][NTOT]
#pragma unroll
  for (int rt = 0; rt < 2; ++rt)
#pragma unroll
    for (int rg = 0; rg < 4; ++rg) {
      float z = Zr[rt][rg >> 1][rg & 1], p = Pr[rt][rg >> 1][rg & 1];
#pragma unroll
      for (int off = 1; off < 16; off <<= 1) {
        z += __shfl_xor(z, off);
        p += __shfl_xor(p, off);
      }
      if (l15 == 0) {
        const int row = rowW + rt * 16 + l4 * 4 + rg;
        atomicAdd(&Zrow[branch * NTOT + row], z);
        atomicAdd(&Prow[branch * NTOT + row], p);
      }
    }
}

// ---------------- loss: per-row loss -> scalar (single block) ---------------
__global__ __launch_bounds__(1024) void loss_kernel(const float* __restrict__ zp,
                                                    const int* __restrict__ lo,
                                                    const int* __restrict__ hi,
                                                    float* __restrict__ out) {
  const int tid = threadIdx.x;
  const float* Zrow = zp;
  const float* Prow = zp + 2 * NTOT;
  float local = 0.f;
  for (int idx = tid; idx < 2 * NTOT; idx += 1024) {
    const int row = (idx >= NTOT) ? idx - NTOT : idx;
    const float z = Zrow[idx];
    const float p = Prow[idx];
    const float C = (float)(hi[row] - lo[row] - 1);
    const float denom = INVT + logf(z);
    local += -((INVT * (p - 1.0f)) / C - denom);
  }
  __shared__ float s[1024];
  s[tid] = local;
  __syncthreads();
  for (int st = 512; st > 0; st >>= 1) {
    if (tid < st) s[tid] += s[tid + st];
    __syncthreads();
  }
  if (tid == 0) {
    const float v = s[0] / (2.0f * NTOT);
    out[0] = v; out[1] = v; out[2] = v;
  }
}

// ---------------------------------------------------------------------------
extern "C" void kernel_launch(void* const* d_in, const int* in_sizes, int n_in,
                              void* d_out, int out_size, void* d_ws,
                              size_t ws_size, hipStream_t stream) {
  const float* features = (const float*)d_in[0];  // (1024,1,128) f32
  const int* label = (const int*)d_in[1];         // (512,) i32
  const float* bank1 = (const float*)d_in[2];     // (128,8192) f32
  const float* bank2 = (const float*)d_in[3];     // (128,8192) f32
  const int* bank_labels = (const int*)d_in[4];   // (8192,) i32
  float* out = (float*)d_out;

  char* ws = (char*)d_ws;
  ushort* cf1b = (ushort*)(ws);            // 2,228,224 B
  ushort* cf2b = (ushort*)(ws + 2228224);  // 2,228,224 B
  int* inv = (int*)(ws + 4456448);         // 34,816 B
  int* lo = (int*)(ws + 4491264);          // 34,816 B
  int* hi = (int*)(ws + 4526080);          // 34,816 B
  float* zp = (float*)(ws + 4560896);      // 139,264 B (Z[2][N], P[2][N])

  prep_kernel<<<dim3(1), dim3(1024), 0, stream>>>(bank_labels, label, inv, lo,
                                                  hi);
  pack_kernel<<<dim3(272, DIM / 32, 2), dim3(32, 8), 0, stream>>>(
      features, bank1, bank2, inv, cf1b, cf2b, zp);
  supcon_mfma_kernel<<<dim3(NTOT / 128, NCHUNK, 2), dim3(256), 0, stream>>>(
      cf1b, cf2b, lo, hi, zp);
  loss_kernel<<<dim3(1), dim3(1024), 0, stream>>>(zp, lo, hi, out);
}